// Round 2
// baseline (325.201 us; speedup 1.0000x reference)
//
#include <hip/hip_runtime.h>
#include <math.h>

#define TPB 256
#define NBLOCKS 2048

// ws layout (all zero-initialized by memset each launch):
// [0] double ce_sum
// [1] u64 c01  (TN | FP<<32)
// [2] u64 c23  (FN | TP<<32)
// [3] u32 ticket

__global__ __launch_bounds__(TPB) void detloss_main(
    const float4* __restrict__ out4,   // outputs as float4 (2 elements each)
    const int4*   __restrict__ lab4,   // labels as int4 (4 elements each)
    double* __restrict__ ce_sum,
    unsigned long long* __restrict__ c01,
    unsigned long long* __restrict__ c23,
    unsigned int* __restrict__ ticket,
    float* __restrict__ out,
    int nchunks, int B)
{
    float ce = 0.0f;
    unsigned long long cnt = 0ull;     // 4 x 16-bit fields: idx = label*2 + pred

    const int stride = gridDim.x * blockDim.x;
    for (int g = blockIdx.x * blockDim.x + threadIdx.x; g < nchunks; g += stride) {
        const int4   lb = lab4[g];
        const float4 a  = out4[2 * g];
        const float4 b  = out4[2 * g + 1];

        // elem: d = o0-o1; pred = (d<0); ce += relu(l? d : -d) + log(1+exp(-|d|))
        {
            const float d = a.x - a.y; const int l = lb.x;
            ce += fmaxf(l ? d : -d, 0.0f) + __logf(1.0f + __expf(-fabsf(d)));
            cnt += 1ull << ((((l << 1) | (d < 0.0f ? 1 : 0))) << 4);
        }
        {
            const float d = a.z - a.w; const int l = lb.y;
            ce += fmaxf(l ? d : -d, 0.0f) + __logf(1.0f + __expf(-fabsf(d)));
            cnt += 1ull << ((((l << 1) | (d < 0.0f ? 1 : 0))) << 4);
        }
        {
            const float d = b.x - b.y; const int l = lb.z;
            ce += fmaxf(l ? d : -d, 0.0f) + __logf(1.0f + __expf(-fabsf(d)));
            cnt += 1ull << ((((l << 1) | (d < 0.0f ? 1 : 0))) << 4);
        }
        {
            const float d = b.z - b.w; const int l = lb.w;
            ce += fmaxf(l ? d : -d, 0.0f) + __logf(1.0f + __expf(-fabsf(d)));
            cnt += 1ull << ((((l << 1) | (d < 0.0f ? 1 : 0))) << 4);
        }
    }

    // wave (64-lane) shuffle reduction
    #pragma unroll
    for (int off = 32; off > 0; off >>= 1) {
        ce  += __shfl_down(ce, off);
        cnt += __shfl_down(cnt, off);
    }

    __shared__ float              s_ce[TPB / 64];
    __shared__ unsigned long long s_cnt[TPB / 64];
    const int wave = threadIdx.x >> 6;
    const int lane = threadIdx.x & 63;
    if (lane == 0) { s_ce[wave] = ce; s_cnt[wave] = cnt; }
    __syncthreads();

    if (threadIdx.x == 0) {
        float bce = 0.0f;
        unsigned long long bc = 0ull;
        #pragma unroll
        for (int w = 0; w < TPB / 64; ++w) { bce += s_ce[w]; bc += s_cnt[w]; }
        atomicAdd(ce_sum, (double)bce);
        const unsigned long long f0 =  bc        & 0xffffull;  // TN
        const unsigned long long f1 = (bc >> 16) & 0xffffull;  // FP
        const unsigned long long f2 = (bc >> 32) & 0xffffull;  // FN
        const unsigned long long f3 = (bc >> 48) & 0xffffull;  // TP
        atomicAdd(c01, f0 | (f1 << 32));
        atomicAdd(c23, f2 | (f3 << 32));
        __threadfence();

        // last block finalizes
        const unsigned int done = atomicAdd(ticket, 1u);
        if (done == gridDim.x - 1) {
            const double ceT = atomicAdd(ce_sum, 0.0);           // device-scope read
            const unsigned long long pa = atomicAdd(c01, 0ull);
            const unsigned long long pb = atomicAdd(c23, 0ull);
            const double TN = (double)(pa & 0xffffffffull);
            const double FP = (double)(pa >> 32);
            const double FN = (double)(pb & 0xffffffffull);
            const double TP = (double)(pb >> 32);
            const double invB = 1.0 / (double)B;
            const bool nonzero = (TP > 0.0) && (TN > 0.0) && (FP > 0.0) && (FN > 0.0);
            const double ratio = (TP / fmax(TP + FN, 1.0)) * (FP / fmax(FP + TN, 1.0));
            const double coeff = nonzero ? (-0.5 * log(sqrt(fmax(ratio, 1e-30)))) : 0.5;
            // N_CLASSES=2: M[pred,label]==1 only when pred=0 & label=1 => sum(CS) == FN
            out[0] = (float)(ceT * invB + coeff * FN * invB);
        }
    }
}

extern "C" void kernel_launch(void* const* d_in, const int* in_sizes, int n_in,
                              void* d_out, int out_size, void* d_ws, size_t ws_size,
                              hipStream_t stream) {
    const float* outputs = (const float*)d_in[0];
    const int*   labels  = (const int*)d_in[1];
    const int B = in_sizes[1];

    double*             ce_sum = (double*)d_ws;
    unsigned long long* c01    = (unsigned long long*)d_ws + 1;
    unsigned long long* c23    = (unsigned long long*)d_ws + 2;
    unsigned int*       ticket = (unsigned int*)((char*)d_ws + 24);

    hipMemsetAsync(d_ws, 0, 64, stream);

    const int nchunks = B / 4;  // B = 2^24, divisible by 4
    detloss_main<<<NBLOCKS, TPB, 0, stream>>>(
        (const float4*)outputs, (const int4*)labels,
        ce_sum, c01, c23, ticket, (float*)d_out, nchunks, B);
}

// Round 3
// 233.643 us; speedup vs baseline: 1.3919x; 1.3919x over previous
//
#include <hip/hip_runtime.h>
#include <math.h>

#define TPB 256
#define NBLOCKS 2048

// ws layout: double ce_part[NBLOCKS] ; unsigned long long cnt_part[NBLOCKS]
// No zero-init needed: every block writes its slot unconditionally each launch.

__device__ __forceinline__ void proc(float o0, float o1, int l,
                                     float& ce, unsigned long long& cnt) {
    // d = o0-o1; pred = (d<0); ce += relu(l? d : -d) + log(1+exp(-|d|))
    const float d = o0 - o1;
    ce += fmaxf(l ? d : -d, 0.0f) + __logf(1.0f + __expf(-fabsf(d)));
    cnt += 1ull << ((((l << 1) | (d < 0.0f ? 1 : 0))) << 4);  // field idx = label*2+pred
}

__global__ __launch_bounds__(TPB) void detloss_main(
    const float4* __restrict__ out4,   // outputs as float4 (2 elements each)
    const int4*   __restrict__ lab4,   // labels as int4 (4 elements each)
    double* __restrict__ ce_part,
    unsigned long long* __restrict__ cnt_part,
    int nchunks)
{
    float ce = 0.0f;
    unsigned long long cnt = 0ull;     // 4 x 16-bit fields (<=32 per field per thread)
    const int tid = threadIdx.x;
    const int nfull = nchunks / (TPB * 4);   // full block-tiles of 4*TPB chunks

    // 4 block-strided chunks per iteration: 12 independent loads in flight.
    for (int t = blockIdx.x; t < nfull; t += gridDim.x) {
        const int g0 = t * (TPB * 4) + tid;
        const int g1 = g0 + TPB, g2 = g1 + TPB, g3 = g2 + TPB;
        const int4 lb0 = lab4[g0], lb1 = lab4[g1], lb2 = lab4[g2], lb3 = lab4[g3];
        const float4 a0 = out4[2*g0], b0 = out4[2*g0+1];
        const float4 a1 = out4[2*g1], b1 = out4[2*g1+1];
        const float4 a2 = out4[2*g2], b2 = out4[2*g2+1];
        const float4 a3 = out4[2*g3], b3 = out4[2*g3+1];

        proc(a0.x,a0.y,lb0.x,ce,cnt); proc(a0.z,a0.w,lb0.y,ce,cnt);
        proc(b0.x,b0.y,lb0.z,ce,cnt); proc(b0.z,b0.w,lb0.w,ce,cnt);
        proc(a1.x,a1.y,lb1.x,ce,cnt); proc(a1.z,a1.w,lb1.y,ce,cnt);
        proc(b1.x,b1.y,lb1.z,ce,cnt); proc(b1.z,b1.w,lb1.w,ce,cnt);
        proc(a2.x,a2.y,lb2.x,ce,cnt); proc(a2.z,a2.w,lb2.y,ce,cnt);
        proc(b2.x,b2.y,lb2.z,ce,cnt); proc(b2.z,b2.w,lb2.w,ce,cnt);
        proc(a3.x,a3.y,lb3.x,ce,cnt); proc(a3.z,a3.w,lb3.y,ce,cnt);
        proc(b3.x,b3.y,lb3.z,ce,cnt); proc(b3.z,b3.w,lb3.w,ce,cnt);
    }

    // tail (empty for B = 2^24)
    for (int g = nfull * (TPB * 4) + blockIdx.x * TPB + tid; g < nchunks;
         g += gridDim.x * TPB) {
        const int4 lb = lab4[g];
        const float4 a = out4[2*g], b = out4[2*g+1];
        proc(a.x,a.y,lb.x,ce,cnt); proc(a.z,a.w,lb.y,ce,cnt);
        proc(b.x,b.y,lb.z,ce,cnt); proc(b.z,b.w,lb.w,ce,cnt);
    }

    // wave (64-lane) shuffle reduction
    #pragma unroll
    for (int off = 32; off > 0; off >>= 1) {
        ce  += __shfl_down(ce, off);
        cnt += __shfl_down(cnt, off);
    }

    __shared__ float              s_ce[TPB / 64];
    __shared__ unsigned long long s_cnt[TPB / 64];
    const int wave = tid >> 6;
    const int lane = tid & 63;
    if (lane == 0) { s_ce[wave] = ce; s_cnt[wave] = cnt; }
    __syncthreads();

    if (tid == 0) {
        float bce = 0.0f;
        unsigned long long bc = 0ull;   // block totals <= 8192 per field, fits 16 bits
        #pragma unroll
        for (int w = 0; w < TPB / 64; ++w) { bce += s_ce[w]; bc += s_cnt[w]; }
        ce_part[blockIdx.x]  = (double)bce;   // plain stores to unique slots — no atomics
        cnt_part[blockIdx.x] = bc;
    }
}

__global__ __launch_bounds__(TPB) void detloss_final(
    const double* __restrict__ ce_part,
    const unsigned long long* __restrict__ cnt_part,
    float* __restrict__ out, int B, int nparts)
{
    double ce = 0.0;
    // unpack BEFORE cross-block summation (16-bit fields would overflow)
    unsigned int q0 = 0, q1 = 0, q2 = 0, q3 = 0;
    for (int s = threadIdx.x; s < nparts; s += TPB) {
        ce += ce_part[s];
        const unsigned long long c = cnt_part[s];
        q0 += (unsigned int)( c        & 0xffffull);  // TN
        q1 += (unsigned int)((c >> 16) & 0xffffull);  // FP
        q2 += (unsigned int)((c >> 32) & 0xffffull);  // FN
        q3 += (unsigned int)( c >> 48);               // TP
    }

    #pragma unroll
    for (int off = 32; off > 0; off >>= 1) {
        ce += __shfl_down(ce, off);
        q0 += __shfl_down(q0, off);
        q1 += __shfl_down(q1, off);
        q2 += __shfl_down(q2, off);
        q3 += __shfl_down(q3, off);
    }

    __shared__ double       s_ce[TPB / 64];
    __shared__ unsigned int s_q[4][TPB / 64];
    const int wave = threadIdx.x >> 6;
    const int lane = threadIdx.x & 63;
    if (lane == 0) {
        s_ce[wave] = ce;
        s_q[0][wave] = q0; s_q[1][wave] = q1; s_q[2][wave] = q2; s_q[3][wave] = q3;
    }
    __syncthreads();

    if (threadIdx.x == 0) {
        double ceT = 0.0;
        unsigned int TNu = 0, FPu = 0, FNu = 0, TPu = 0;
        #pragma unroll
        for (int w = 0; w < TPB / 64; ++w) {
            ceT += s_ce[w];
            TNu += s_q[0][w]; FPu += s_q[1][w]; FNu += s_q[2][w]; TPu += s_q[3][w];
        }
        const double TN = (double)TNu, FP = (double)FPu,
                     FN = (double)FNu, TP = (double)TPu;
        const double invB = 1.0 / (double)B;
        const bool nonzero = (TP > 0.0) && (TN > 0.0) && (FP > 0.0) && (FN > 0.0);
        const double ratio = (TP / fmax(TP + FN, 1.0)) * (FP / fmax(FP + TN, 1.0));
        const double coeff = nonzero ? (-0.5 * log(sqrt(fmax(ratio, 1e-30)))) : 0.5;
        // N_CLASSES=2: M[pred,label]==1 only when pred=0 & label=1 => sum(CS) == FN
        out[0] = (float)(ceT * invB + coeff * FN * invB);
    }
}

extern "C" void kernel_launch(void* const* d_in, const int* in_sizes, int n_in,
                              void* d_out, int out_size, void* d_ws, size_t ws_size,
                              hipStream_t stream) {
    const float* outputs = (const float*)d_in[0];
    const int*   labels  = (const int*)d_in[1];
    const int B = in_sizes[1];

    double*             ce_part  = (double*)d_ws;
    unsigned long long* cnt_part = (unsigned long long*)((char*)d_ws
                                                         + NBLOCKS * sizeof(double));

    const int nchunks = B / 4;  // B = 2^24, divisible by 4
    detloss_main<<<NBLOCKS, TPB, 0, stream>>>(
        (const float4*)outputs, (const int4*)labels, ce_part, cnt_part, nchunks);
    detloss_final<<<1, TPB, 0, stream>>>(ce_part, cnt_part, (float*)d_out, B, NBLOCKS);
}

// Round 5
// 216.622 us; speedup vs baseline: 1.5012x; 1.0786x over previous
//
#include <hip/hip_runtime.h>
#include <math.h>

#define TPB 256
#define CHUNKS_PER_BLOCK (TPB * 4)   // 4 int4-label chunks per thread
#define TPB_F 1024

typedef float fx4 __attribute__((ext_vector_type(4)));
typedef int   ix4 __attribute__((ext_vector_type(4)));

// ws layout: double ce_part[nparts] ; unsigned long long cnt_part[nparts]
// No zero-init needed: every block writes its slot unconditionally each launch.

__device__ __forceinline__ void proc(float o0, float o1, int l,
                                     float& ce, unsigned long long& cnt) {
    // d = o0-o1; pred = (d<0); ce += relu(l? d : -d) + log(1+exp(-|d|))
    const float d = o0 - o1;
    ce += fmaxf(l ? d : -d, 0.0f) + __logf(1.0f + __expf(-fabsf(d)));
    cnt += 1ull << ((((l << 1) | (d < 0.0f ? 1 : 0))) << 4);  // field = label*2+pred
}

__global__ __launch_bounds__(TPB) void detloss_main(
    const fx4* __restrict__ out4,   // outputs as float4 (2 elements each)
    const ix4* __restrict__ lab4,   // labels as int4 (4 elements each)
    double* __restrict__ ce_part,
    unsigned long long* __restrict__ cnt_part,
    int nchunks)
{
    float ce = 0.0f;
    unsigned long long cnt = 0ull;     // 4 x 16-bit fields (<=16 per field per thread)
    const int tid = threadIdx.x;
    const int g0 = blockIdx.x * CHUNKS_PER_BLOCK + tid;
    const int g1 = g0 + TPB, g2 = g1 + TPB, g3 = g2 + TPB;

    if (g3 < nchunks) {
        // fast path: all 12 loads issued up front, nontemporal (read-once stream)
        const ix4 lb0 = __builtin_nontemporal_load(lab4 + g0);
        const ix4 lb1 = __builtin_nontemporal_load(lab4 + g1);
        const ix4 lb2 = __builtin_nontemporal_load(lab4 + g2);
        const ix4 lb3 = __builtin_nontemporal_load(lab4 + g3);
        const fx4 a0 = __builtin_nontemporal_load(out4 + 2*g0);
        const fx4 b0 = __builtin_nontemporal_load(out4 + 2*g0 + 1);
        const fx4 a1 = __builtin_nontemporal_load(out4 + 2*g1);
        const fx4 b1 = __builtin_nontemporal_load(out4 + 2*g1 + 1);
        const fx4 a2 = __builtin_nontemporal_load(out4 + 2*g2);
        const fx4 b2 = __builtin_nontemporal_load(out4 + 2*g2 + 1);
        const fx4 a3 = __builtin_nontemporal_load(out4 + 2*g3);
        const fx4 b3 = __builtin_nontemporal_load(out4 + 2*g3 + 1);

        proc(a0.x,a0.y,lb0.x,ce,cnt); proc(a0.z,a0.w,lb0.y,ce,cnt);
        proc(b0.x,b0.y,lb0.z,ce,cnt); proc(b0.z,b0.w,lb0.w,ce,cnt);
        proc(a1.x,a1.y,lb1.x,ce,cnt); proc(a1.z,a1.w,lb1.y,ce,cnt);
        proc(b1.x,b1.y,lb1.z,ce,cnt); proc(b1.z,b1.w,lb1.w,ce,cnt);
        proc(a2.x,a2.y,lb2.x,ce,cnt); proc(a2.z,a2.w,lb2.y,ce,cnt);
        proc(b2.x,b2.y,lb2.z,ce,cnt); proc(b2.z,b2.w,lb2.w,ce,cnt);
        proc(a3.x,a3.y,lb3.x,ce,cnt); proc(a3.z,a3.w,lb3.y,ce,cnt);
        proc(b3.x,b3.y,lb3.z,ce,cnt); proc(b3.z,b3.w,lb3.w,ce,cnt);
    } else {
        // tail blocks (unused for B = 2^24): per-chunk guards
        #pragma unroll
        for (int k = 0; k < 4; ++k) {
            const int g = g0 + k * TPB;
            if (g < nchunks) {
                const ix4 lb = lab4[g];
                const fx4 a = out4[2*g], b = out4[2*g+1];
                proc(a.x,a.y,lb.x,ce,cnt); proc(a.z,a.w,lb.y,ce,cnt);
                proc(b.x,b.y,lb.z,ce,cnt); proc(b.z,b.w,lb.w,ce,cnt);
            }
        }
    }

    // wave (64-lane) shuffle reduction
    #pragma unroll
    for (int off = 32; off > 0; off >>= 1) {
        ce  += __shfl_down(ce, off);
        cnt += __shfl_down(cnt, off);
    }

    __shared__ float              s_ce[TPB / 64];
    __shared__ unsigned long long s_cnt[TPB / 64];
    const int wave = tid >> 6;
    const int lane = tid & 63;
    if (lane == 0) { s_ce[wave] = ce; s_cnt[wave] = cnt; }
    __syncthreads();

    if (tid == 0) {
        float bce = 0.0f;
        unsigned long long bc = 0ull;   // block totals <= 4096/field, fits 16 bits
        #pragma unroll
        for (int w = 0; w < TPB / 64; ++w) { bce += s_ce[w]; bc += s_cnt[w]; }
        ce_part[blockIdx.x]  = (double)bce;   // unique slots — no atomics
        cnt_part[blockIdx.x] = bc;
    }
}

__global__ __launch_bounds__(TPB_F) void detloss_final(
    const double* __restrict__ ce_part,
    const unsigned long long* __restrict__ cnt_part,
    float* __restrict__ out, int B, int nparts)
{
    double ce = 0.0;
    // unpack BEFORE cross-block summation (16-bit fields would overflow)
    unsigned int q0 = 0, q1 = 0, q2 = 0, q3 = 0;
    for (int s = threadIdx.x; s < nparts; s += TPB_F) {
        ce += ce_part[s];
        const unsigned long long c = cnt_part[s];
        q0 += (unsigned int)( c        & 0xffffull);  // TN
        q1 += (unsigned int)((c >> 16) & 0xffffull);  // FP
        q2 += (unsigned int)((c >> 32) & 0xffffull);  // FN
        q3 += (unsigned int)( c >> 48);               // TP
    }

    #pragma unroll
    for (int off = 32; off > 0; off >>= 1) {
        ce += __shfl_down(ce, off);
        q0 += __shfl_down(q0, off);
        q1 += __shfl_down(q1, off);
        q2 += __shfl_down(q2, off);
        q3 += __shfl_down(q3, off);
    }

    __shared__ double       s_ce[TPB_F / 64];
    __shared__ unsigned int s_q[4][TPB_F / 64];
    const int wave = threadIdx.x >> 6;
    const int lane = threadIdx.x & 63;
    if (lane == 0) {
        s_ce[wave] = ce;
        s_q[0][wave] = q0; s_q[1][wave] = q1; s_q[2][wave] = q2; s_q[3][wave] = q3;
    }
    __syncthreads();

    if (threadIdx.x == 0) {
        double ceT = 0.0;
        unsigned int TNu = 0, FPu = 0, FNu = 0, TPu = 0;
        #pragma unroll
        for (int w = 0; w < TPB_F / 64; ++w) {
            ceT += s_ce[w];
            TNu += s_q[0][w]; FPu += s_q[1][w]; FNu += s_q[2][w]; TPu += s_q[3][w];
        }
        const double TN = (double)TNu, FP = (double)FPu,
                     FN = (double)FNu, TP = (double)TPu;
        const double invB = 1.0 / (double)B;
        const bool nonzero = (TP > 0.0) && (TN > 0.0) && (FP > 0.0) && (FN > 0.0);
        const double ratio = (TP / fmax(TP + FN, 1.0)) * (FP / fmax(FP + TN, 1.0));
        const double coeff = nonzero ? (-0.5 * log(sqrt(fmax(ratio, 1e-30)))) : 0.5;
        // N_CLASSES=2: M[pred,label]==1 only when pred=0 & label=1 => sum(CS) == FN
        out[0] = (float)(ceT * invB + coeff * FN * invB);
    }
}

extern "C" void kernel_launch(void* const* d_in, const int* in_sizes, int n_in,
                              void* d_out, int out_size, void* d_ws, size_t ws_size,
                              hipStream_t stream) {
    const float* outputs = (const float*)d_in[0];
    const int*   labels  = (const int*)d_in[1];
    const int B = in_sizes[1];

    const int nchunks = B / 4;                                   // B = 2^24
    const int nparts  = (nchunks + CHUNKS_PER_BLOCK - 1) / CHUNKS_PER_BLOCK;  // 4096

    double*             ce_part  = (double*)d_ws;
    unsigned long long* cnt_part = (unsigned long long*)((char*)d_ws
                                                         + (size_t)nparts * sizeof(double));

    detloss_main<<<nparts, TPB, 0, stream>>>(
        (const fx4*)outputs, (const ix4*)labels, ce_part, cnt_part, nchunks);
    detloss_final<<<1, TPB_F, 0, stream>>>(ce_part, cnt_part, (float*)d_out, B, nparts);
}